// Round 15
// baseline (959.219 us; speedup 1.0000x reference)
//
#include <hip/hip_runtime.h>
#include <math.h>

#define NN 50000
#define EE 800000
#define ET (EE + NN)            // CSR slots incl. self-loops
#define FIN 128
#define HH 8
#define CC 64
#define HC 512
#define HU 256                  // h row in uints (2 bf16 per uint)
#define GG 64
#define POOL_SZ (GG * 3 * CC)   // 12288

typedef short short8 __attribute__((ext_vector_type(8)));
typedef float floatx4 __attribute__((ext_vector_type(4)));

__device__ __forceinline__ unsigned bf16pack(float a, float b) {
    unsigned ua = __float_as_uint(a), ub = __float_as_uint(b);
    ua = (ua + 0x7FFFu + ((ua >> 16) & 1u)) >> 16;          // RNE
    ub = (ub + 0x7FFFu + ((ub >> 16) & 1u)) >> 16;
    return ua | (ub << 16);
}
__device__ __forceinline__ unsigned short bf16r(float a) {
    unsigned ua = __float_as_uint(a);
    return (unsigned short)((ua + 0x7FFFu + ((ua >> 16) & 1u)) >> 16);
}
__device__ __forceinline__ float bf_lo(unsigned u) { return __uint_as_float(u << 16); }
__device__ __forceinline__ float bf_hi(unsigned u) { return __uint_as_float(u & 0xFFFF0000u); }

// ---------------- fused prep: x f32->bf16 + cnt init ----------------

__global__ void k_prep(const float* __restrict__ in, unsigned* __restrict__ out, int* cnt) {
    int i = blockIdx.x * blockDim.x + threadIdx.x;
    if (i < NN * FIN / 8) {
        float4 a = ((const float4*)in)[i * 2];
        float4 b = ((const float4*)in)[i * 2 + 1];
        uint4 o;
        o.x = bf16pack(a.x, a.y); o.y = bf16pack(a.z, a.w);
        o.z = bf16pack(b.x, b.y); o.w = bf16pack(b.z, b.w);
        ((uint4*)out)[i] = o;
    }
    if (i < NN) cnt[i] = 1;                 // reserve self-loop slot
}

// ---------------- CSR build ----------------

__global__ void k_count(const int* __restrict__ dst, int* cnt) {
    int e = blockIdx.x * blockDim.x + threadIdx.x;
    if (e < EE) atomicAdd(&cnt[dst[e]], 1);
}

// single-block scan of cnt -> off/cursor + self-loop col fill
__global__ __launch_bounds__(1024) void k_scanall(
        const int* __restrict__ cnt, int* __restrict__ off,
        int* __restrict__ cursor, int* __restrict__ col) {
    __shared__ int s[1024];
    const int t = threadIdx.x;
    const int CPT = (NN + 1023) / 1024;     // 49
    int base = t * CPT;
    int lim = NN - base;
    if (lim < 0) lim = 0;
    if (lim > CPT) lim = CPT;
    int sum = 0;
    for (int i = 0; i < lim; ++i) sum += cnt[base + i];
    s[t] = sum;
    __syncthreads();
    for (int d = 1; d < 1024; d <<= 1) {
        int v = (t >= d) ? s[t - d] : 0;
        __syncthreads();
        s[t] += v;
        __syncthreads();
    }
    int run = s[t] - sum;                   // exclusive prefix
    for (int i = 0; i < lim; ++i) {
        int c = cnt[base + i];
        off[base + i] = run;
        cursor[base + i] = run + 1;         // slot run = self loop
        col[run] = base + i;
        run += c;
    }
    if (t == 0) off[NN] = ET;
}

__global__ void k_fill(const int* __restrict__ src, const int* __restrict__ dst,
                       int* cursor, int* col) {
    int e = blockIdx.x * blockDim.x + threadIdx.x;
    if (e < EE) {
        int p = atomicAdd(&cursor[dst[e]], 1);
        col[p] = src[e];
    }
}

// ---------------- MFMA GEMM + fused a_src/a_dst epilogue; h bf16 ----------------

template<int K>
__global__ __launch_bounds__(256) void k_gemm_mfma(
        const unsigned short* __restrict__ A,   // bf16 [M][K]
        const float* __restrict__ W,            // f32  [K][512]
        const float* __restrict__ asrc, const float* __restrict__ adst,
        unsigned short* __restrict__ hout,      // bf16 [M][512]
        float* __restrict__ as_out, float* __restrict__ ad_out, int M) {
    __shared__ unsigned short Asl[4][64][8];
    __shared__ unsigned short Bsl[4][64][8];
    const int row0 = blockIdx.x * 64;
    const int head = blockIdx.y;
    const int col0 = head * 64;
    const int tid  = threadIdx.x;
    const int w    = tid >> 6;
    const int lane = tid & 63;
    const int kgl  = lane >> 4;      // k-group this lane supplies
    const int l15  = lane & 15;

    floatx4 acc[4] = {};             // 4 col-fragments x 4 f32

    const int kgs = tid >> 6;        // staging k-group
    const int rc  = tid & 63;        // staging row/col

    for (int kt = 0; kt < K; kt += 32) {
        uint4 av = make_uint4(0, 0, 0, 0);
        if (row0 + rc < M)
            av = *(const uint4*)(A + (size_t)(row0 + rc) * K + kt + kgs * 8);
        *(uint4*)&Asl[kgs][rc][0] = av;
        float wv[8];
        #pragma unroll
        for (int e = 0; e < 8; ++e)
            wv[e] = W[(size_t)(kt + kgs * 8 + e) * HC + col0 + rc];
        uint4 bv;
        bv.x = bf16pack(wv[0], wv[1]); bv.y = bf16pack(wv[2], wv[3]);
        bv.z = bf16pack(wv[4], wv[5]); bv.w = bf16pack(wv[6], wv[7]);
        *(uint4*)&Bsl[kgs][rc][0] = bv;
        __syncthreads();

        short8 af = *(const short8*)&Asl[kgl][16 * w + l15][0];
        #pragma unroll
        for (int fj = 0; fj < 4; ++fj) {
            short8 bf = *(const short8*)&Bsl[kgl][16 * fj + l15][0];
            acc[fj] = __builtin_amdgcn_mfma_f32_16x16x32_bf16(af, bf, acc[fj], 0, 0, 0);
        }
        __syncthreads();
    }

    float sav[4], dav[4];
    #pragma unroll
    for (int fj = 0; fj < 4; ++fj) {
        sav[fj] = asrc[col0 + 16 * fj + l15];
        dav[fj] = adst[col0 + 16 * fj + l15];
    }
    const int r4 = lane >> 4;
    #pragma unroll
    for (int reg = 0; reg < 4; ++reg) {
        int gr = row0 + 16 * w + r4 * 4 + reg;
        float ps = acc[0][reg] * sav[0] + acc[1][reg] * sav[1]
                 + acc[2][reg] * sav[2] + acc[3][reg] * sav[3];
        float pd = acc[0][reg] * dav[0] + acc[1][reg] * dav[1]
                 + acc[2][reg] * dav[2] + acc[3][reg] * dav[3];
        ps += __shfl_xor(ps, 1); ps += __shfl_xor(ps, 2);
        ps += __shfl_xor(ps, 4); ps += __shfl_xor(ps, 8);
        pd += __shfl_xor(pd, 1); pd += __shfl_xor(pd, 2);
        pd += __shfl_xor(pd, 4); pd += __shfl_xor(pd, 8);
        if (gr < M) {
            #pragma unroll
            for (int fj = 0; fj < 4; ++fj)
                hout[(size_t)gr * HC + col0 + 16 * fj + l15] = bf16r(acc[fj][reg]);
            if (l15 == 0) {
                as_out[gr * HH + head] = ps;
                ad_out[gr * HH + head] = pd;
            }
        }
    }
}

// ---------------- 2-waves-per-node softmax + gather (no max-shift) ----------------
// 256 threads = 4 waves = 2 nodes/block; waves (wv=0,1) of a node each own half
// the 1KB bf16 row (2 u32/lane) and 4 heads. Per-edge dependent work halved vs
// the 1-wave version. One barrier per node merges head partials at the end.

__global__ __launch_bounds__(256) void k_aggw(
        const unsigned* __restrict__ hb, const float* __restrict__ as,
        const float* __restrict__ ad, const int* __restrict__ off,
        const int* __restrict__ col, const float* __restrict__ bias,
        float* __restrict__ yout, unsigned* __restrict__ yb) {
    __shared__ float s_alpha[2][2][64][4];
    __shared__ int   s_src[2][2][64];
    __shared__ float2 s_red[2][32];

    const int wv   = (threadIdx.x >> 6) & 1;     // wave within node
    const int nd   = threadIdx.x >> 7;           // node within block
    const int lane = threadIdx.x & 63;
    const int n    = blockIdx.x * 2 + nd;        // 25000*2 == NN exactly
    const int e0   = off[n];
    const int tot  = off[n + 1] - e0;            // >=1 (self loop in CSR)
    const int hsel = lane >> 5;

    float4 adv = *(const float4*)&ad[n * HH + 4 * wv];   // this wave's 4 heads

    float d0 = 0.f, d1 = 0.f;                    // denom: heads 4wv+hsel, 4wv+2+hsel
    float acc[4] = {0.f, 0.f, 0.f, 0.f};

    for (int base = 0; base < tot; base += 64) {
        const int cnt = min(64, tot - base);
        // ---- phase A: numerators for this wave's 4 heads ----
        float n0, n1, n2, n3;
        if (lane < cnt) {
            int s = col[e0 + base + lane];
            s_src[nd][wv][lane] = s;
            float4 a = *(const float4*)&as[s * HH + 4 * wv];
            float e0v = a.x + adv.x, e1v = a.y + adv.y;
            float e2v = a.z + adv.z, e3v = a.w + adv.w;
            e0v = e0v > 0.f ? e0v : 0.2f * e0v;
            e1v = e1v > 0.f ? e1v : 0.2f * e1v;
            e2v = e2v > 0.f ? e2v : 0.2f * e2v;
            e3v = e3v > 0.f ? e3v : 0.2f * e3v;
            n0 = __expf(e0v); n1 = __expf(e1v);
            n2 = __expf(e2v); n3 = __expf(e3v);
            *(float4*)&s_alpha[nd][wv][lane][0] = make_float4(n0, n1, n2, n3);
        } else {
            n0 = n1 = n2 = n3 = 0.f;
        }
        // denom butterflies (4 heads)
        #define RED(v) { v += __shfl_xor(v, 1);  v += __shfl_xor(v, 2); \
                         v += __shfl_xor(v, 4);  v += __shfl_xor(v, 8); \
                         v += __shfl_xor(v, 16); v += __shfl_xor(v, 32); }
        RED(n0); RED(n1); RED(n2); RED(n3);
        #undef RED
        d0 += hsel ? n1 : n0;
        d1 += hsel ? n3 : n2;
        // ---- phase B: gather (2 u32 per lane per edge) ----
        #define STEP(jj) { \
            int sj = s_src[nd][wv][jj]; \
            const unsigned* _p = &hb[(size_t)sj * HU + wv * 128 + lane]; \
            unsigned u0 = _p[0], u1 = _p[64]; \
            float a0 = s_alpha[nd][wv][jj][hsel]; \
            float a1 = s_alpha[nd][wv][jj][2 + hsel]; \
            acc[0] += a0 * bf_lo(u0); acc[1] += a0 * bf_hi(u0); \
            acc[2] += a1 * bf_lo(u1); acc[3] += a1 * bf_hi(u1); }
        int j = 0;
        for (; j + 4 <= cnt; j += 4) { STEP(j); STEP(j + 1); STEP(j + 2); STEP(j + 3); }
        for (; j < cnt; ++j) STEP(j);
        #undef STEP
    }

    // normalize, sum this wave's 2 heads, fold lanes l and l^32
    float r0 = 1.f / d0, r1 = 1.f / d1;
    float sx = acc[0] * r0 + acc[2] * r1;
    float sy = acc[1] * r0 + acc[3] * r1;
    sx += __shfl_xor(sx, 32);
    sy += __shfl_xor(sy, 32);
    if (wv == 1 && lane < 32) s_red[nd][lane] = make_float2(sx, sy);
    __syncthreads();
    if (wv == 0 && lane < 32) {
        float2 o = s_red[nd][lane];
        float2 bv = *(const float2*)&bias[lane * 2];
        float vx = (sx + o.x) * 0.125f + bv.x;
        float vy = (sy + o.y) * 0.125f + bv.y;
        vx = vx > 0.f ? vx : (__expf(vx) - 1.f);
        vy = vy > 0.f ? vy : (__expf(vy) - 1.f);
        *(float2*)&yout[(size_t)n * CC + lane * 2] = make_float2(vx, vy);
        yb[(size_t)n * 32 + lane] = bf16pack(vx, vy);   // bf16 copy for next GEMM
    }
}

// ---------------- per-graph pooling (no atomics) ----------------

__global__ __launch_bounds__(256) void k_pool(
        const float* __restrict__ y, const int* __restrict__ batch,
        float* __restrict__ pooled, int layerOff) {
    __shared__ float red[256];
    const int g = blockIdx.x;
    const int t = threadIdx.x;
    int lo = 0, hi = NN;
    while (lo < hi) { int mid = (lo + hi) >> 1; if (batch[mid] < g) lo = mid + 1; else hi = mid; }
    const int nlo = lo;
    lo = nlo; hi = NN;
    while (lo < hi) { int mid = (lo + hi) >> 1; if (batch[mid] < g + 1) lo = mid + 1; else hi = mid; }
    const int nhi = lo;

    const int c = t & 63, r = t >> 6;
    float sum = 0.f;
    for (int n = nlo + r; n < nhi; n += 4) sum += y[(size_t)n * CC + c];
    red[t] = sum;
    __syncthreads();
    if (t < 64)
        pooled[g * (3 * CC) + layerOff + t] = red[t] + red[t + 64] + red[t + 128] + red[t + 192];
}

// ---------------- launch ----------------

extern "C" void kernel_launch(void* const* d_in, const int* in_sizes, int n_in,
                              void* d_out, int out_size, void* d_ws, size_t ws_size,
                              hipStream_t stream) {
    const float* x      = (const float*)d_in[0];
    const int*   ei     = (const int*)d_in[1];
    const int*   batch  = (const int*)d_in[2];
    const float* W0     = (const float*)d_in[4];
    const float* asrc0  = (const float*)d_in[5];
    const float* adst0  = (const float*)d_in[6];
    const float* b0     = (const float*)d_in[7];
    const float* W1     = (const float*)d_in[8];
    const float* asrc1  = (const float*)d_in[9];
    const float* adst1  = (const float*)d_in[10];
    const float* b1     = (const float*)d_in[11];
    const float* W2     = (const float*)d_in[12];
    const float* asrc2  = (const float*)d_in[13];
    const float* adst2  = (const float*)d_in[14];
    const float* b2     = (const float*)d_in[15];

    const int* src = ei;
    const int* dst = ei + EE;

    float* outp   = (float*)d_out;
    float* pooled = outp;                 // [64,192]
    float* hfinal = outp + POOL_SZ;       // [N,64]

    // workspace layout
    unsigned* hb     = (unsigned*)d_ws;                    // N*256 (bf16 x2)
    float*    y      = (float*)(hb + (size_t)NN * HU);     // N*64
    float*    as_buf = y + (size_t)NN * CC;                // N*8
    float*    ad_buf = as_buf + (size_t)NN * HH;           // N*8
    unsigned* xb     = (unsigned*)(ad_buf + (size_t)NN * HH); // N*64 (bf16 x2)
    unsigned* yb     = xb + (size_t)NN * 64;               // N*32 (bf16 x2)
    int*      off    = (int*)(yb + (size_t)NN * 32);       // N+1
    int*      cursor = off + (NN + 1);                     // N
    int*      cnt    = cursor + NN;                        // N
    int*      col    = cnt + NN;                           // ET

    k_prep<<<(NN * FIN / 8 + 255) / 256, 256, 0, stream>>>(x, xb, cnt);
    k_count<<<(EE + 255) / 256, 256, 0, stream>>>(dst, cnt);
    k_scanall<<<1, 1024, 0, stream>>>(cnt, off, cursor, col);
    k_fill<<<(EE + 255) / 256, 256, 0, stream>>>(src, dst, cursor, col);

    dim3 ggrid((NN + 63) / 64, HH);

    const float* Ws_[3]  = {W0, W1, W2};
    const float* sa_[3]  = {asrc0, asrc1, asrc2};
    const float* da_[3]  = {adst0, adst1, adst2};
    const float* bb_[3]  = {b0, b1, b2};
    float* youts[3] = {y, y, hfinal};

    for (int L = 0; L < 3; ++L) {
        if (L == 0)
            k_gemm_mfma<FIN><<<ggrid, 256, 0, stream>>>(
                (const unsigned short*)xb, Ws_[0], sa_[0], da_[0],
                (unsigned short*)hb, as_buf, ad_buf, NN);
        else
            k_gemm_mfma<CC><<<ggrid, 256, 0, stream>>>(
                (const unsigned short*)yb, Ws_[L], sa_[L], da_[L],
                (unsigned short*)hb, as_buf, ad_buf, NN);
        k_aggw<<<NN / 2, 256, 0, stream>>>(hb, as_buf, ad_buf, off, col,
                                           bb_[L], youts[L], yb);
        k_pool<<<GG, 256, 0, stream>>>(youts[L], batch, pooled, L * CC);
    }
}

// Round 16
// 833.781 us; speedup vs baseline: 1.1504x; 1.1504x over previous
//
#include <hip/hip_runtime.h>
#include <math.h>

#define NN 50000
#define EE 800000
#define ET (EE + NN)            // CSR slots incl. self-loops
#define FIN 128
#define HH 8
#define CC 64
#define HC 512
#define HU 256                  // h row in uints (2 bf16 per uint)
#define GG 64
#define POOL_SZ (GG * 3 * CC)   // 12288

typedef short short8 __attribute__((ext_vector_type(8)));
typedef float floatx4 __attribute__((ext_vector_type(4)));

__device__ __forceinline__ unsigned bf16pack(float a, float b) {
    unsigned ua = __float_as_uint(a), ub = __float_as_uint(b);
    ua = (ua + 0x7FFFu + ((ua >> 16) & 1u)) >> 16;          // RNE
    ub = (ub + 0x7FFFu + ((ub >> 16) & 1u)) >> 16;
    return ua | (ub << 16);
}
__device__ __forceinline__ unsigned short bf16r(float a) {
    unsigned ua = __float_as_uint(a);
    return (unsigned short)((ua + 0x7FFFu + ((ua >> 16) & 1u)) >> 16);
}
__device__ __forceinline__ float bf_lo(unsigned u) { return __uint_as_float(u << 16); }
__device__ __forceinline__ float bf_hi(unsigned u) { return __uint_as_float(u & 0xFFFF0000u); }

// ---------------- fused prep: x f32->bf16 + cnt init ----------------

__global__ void k_prep(const float* __restrict__ in, unsigned* __restrict__ out, int* cnt) {
    int i = blockIdx.x * blockDim.x + threadIdx.x;
    if (i < NN * FIN / 8) {
        float4 a = ((const float4*)in)[i * 2];
        float4 b = ((const float4*)in)[i * 2 + 1];
        uint4 o;
        o.x = bf16pack(a.x, a.y); o.y = bf16pack(a.z, a.w);
        o.z = bf16pack(b.x, b.y); o.w = bf16pack(b.z, b.w);
        ((uint4*)out)[i] = o;
    }
    if (i < NN) cnt[i] = 1;                 // reserve self-loop slot
}

// ---------------- CSR build (multi-block scan chain) ----------------

__global__ void k_count(const int* __restrict__ dst, int* cnt) {
    int e = blockIdx.x * blockDim.x + threadIdx.x;
    if (e < EE) atomicAdd(&cnt[dst[e]], 1);
}

#define SCAN_B 256
__global__ void k_scan1(const int* __restrict__ cnt, int* off, int* bsum, int n) {
    __shared__ int s[SCAN_B];
    int i = blockIdx.x * SCAN_B + threadIdx.x;
    int v = (i < n) ? cnt[i] : 0;
    s[threadIdx.x] = v;
    __syncthreads();
    for (int d = 1; d < SCAN_B; d <<= 1) {
        int t = (threadIdx.x >= d) ? s[threadIdx.x - d] : 0;
        __syncthreads();
        s[threadIdx.x] += t;
        __syncthreads();
    }
    if (i < n) off[i] = s[threadIdx.x] - v;           // local exclusive
    if (threadIdx.x == SCAN_B - 1) bsum[blockIdx.x] = s[SCAN_B - 1];
}

__global__ void k_scan2(int* bsum, int nb) {
    __shared__ int s[SCAN_B];
    int v = (threadIdx.x < nb) ? bsum[threadIdx.x] : 0;
    s[threadIdx.x] = v;
    __syncthreads();
    for (int d = 1; d < SCAN_B; d <<= 1) {
        int t = (threadIdx.x >= d) ? s[threadIdx.x - d] : 0;
        __syncthreads();
        s[threadIdx.x] += t;
        __syncthreads();
    }
    if (threadIdx.x < nb) bsum[threadIdx.x] = s[threadIdx.x] - v;  // exclusive
}

// scan3 + self-loop fill fused
__global__ void k_scan3(int* off, const int* __restrict__ bsum, int* cursor,
                        int* __restrict__ col, int n, int total) {
    int i = blockIdx.x * blockDim.x + threadIdx.x;
    if (i < n) {
        int v = off[i] + bsum[i / SCAN_B];
        off[i] = v;
        cursor[i] = v + 1;                  // slot v = self loop
        col[v] = i;
    }
    if (i == 0) off[n] = total;
}

__global__ void k_fill(const int* __restrict__ src, const int* __restrict__ dst,
                       int* cursor, int* col) {
    int e = blockIdx.x * blockDim.x + threadIdx.x;
    if (e < EE) {
        int p = atomicAdd(&cursor[dst[e]], 1);
        col[p] = src[e];
    }
}

// ---------------- MFMA GEMM + fused a_src/a_dst epilogue; h bf16 ----------------

template<int K>
__global__ __launch_bounds__(256) void k_gemm_mfma(
        const unsigned short* __restrict__ A,   // bf16 [M][K]
        const float* __restrict__ W,            // f32  [K][512]
        const float* __restrict__ asrc, const float* __restrict__ adst,
        unsigned short* __restrict__ hout,      // bf16 [M][512]
        float* __restrict__ as_out, float* __restrict__ ad_out, int M) {
    __shared__ unsigned short Asl[4][64][8];
    __shared__ unsigned short Bsl[4][64][8];
    const int row0 = blockIdx.x * 64;
    const int head = blockIdx.y;
    const int col0 = head * 64;
    const int tid  = threadIdx.x;
    const int w    = tid >> 6;
    const int lane = tid & 63;
    const int kgl  = lane >> 4;      // k-group this lane supplies
    const int l15  = lane & 15;

    floatx4 acc[4] = {};             // 4 col-fragments x 4 f32

    const int kgs = tid >> 6;        // staging k-group
    const int rc  = tid & 63;        // staging row/col

    for (int kt = 0; kt < K; kt += 32) {
        uint4 av = make_uint4(0, 0, 0, 0);
        if (row0 + rc < M)
            av = *(const uint4*)(A + (size_t)(row0 + rc) * K + kt + kgs * 8);
        *(uint4*)&Asl[kgs][rc][0] = av;
        float wv[8];
        #pragma unroll
        for (int e = 0; e < 8; ++e)
            wv[e] = W[(size_t)(kt + kgs * 8 + e) * HC + col0 + rc];
        uint4 bv;
        bv.x = bf16pack(wv[0], wv[1]); bv.y = bf16pack(wv[2], wv[3]);
        bv.z = bf16pack(wv[4], wv[5]); bv.w = bf16pack(wv[6], wv[7]);
        *(uint4*)&Bsl[kgs][rc][0] = bv;
        __syncthreads();

        short8 af = *(const short8*)&Asl[kgl][16 * w + l15][0];
        #pragma unroll
        for (int fj = 0; fj < 4; ++fj) {
            short8 bf = *(const short8*)&Bsl[kgl][16 * fj + l15][0];
            acc[fj] = __builtin_amdgcn_mfma_f32_16x16x32_bf16(af, bf, acc[fj], 0, 0, 0);
        }
        __syncthreads();
    }

    float sav[4], dav[4];
    #pragma unroll
    for (int fj = 0; fj < 4; ++fj) {
        sav[fj] = asrc[col0 + 16 * fj + l15];
        dav[fj] = adst[col0 + 16 * fj + l15];
    }
    const int r4 = lane >> 4;
    #pragma unroll
    for (int reg = 0; reg < 4; ++reg) {
        int gr = row0 + 16 * w + r4 * 4 + reg;
        float ps = acc[0][reg] * sav[0] + acc[1][reg] * sav[1]
                 + acc[2][reg] * sav[2] + acc[3][reg] * sav[3];
        float pd = acc[0][reg] * dav[0] + acc[1][reg] * dav[1]
                 + acc[2][reg] * dav[2] + acc[3][reg] * dav[3];
        ps += __shfl_xor(ps, 1); ps += __shfl_xor(ps, 2);
        ps += __shfl_xor(ps, 4); ps += __shfl_xor(ps, 8);
        pd += __shfl_xor(pd, 1); pd += __shfl_xor(pd, 2);
        pd += __shfl_xor(pd, 4); pd += __shfl_xor(pd, 8);
        if (gr < M) {
            #pragma unroll
            for (int fj = 0; fj < 4; ++fj)
                hout[(size_t)gr * HC + col0 + 16 * fj + l15] = bf16r(acc[fj][reg]);
            if (l15 == 0) {
                as_out[gr * HH + head] = ps;
                ad_out[gr * HH + head] = pd;
            }
        }
    }
}

// ---------------- 2-waves-per-node softmax + gather (no max-shift) ----------------
// 256 threads = 4 waves = 2 nodes/block; waves (wv=0,1) of a node each own half
// the 1KB bf16 row (2 u32/lane) and 4 heads. Per-edge dependent work halved vs
// the 1-wave version. One barrier per node merges head partials at the end.

__global__ __launch_bounds__(256) void k_aggw(
        const unsigned* __restrict__ hb, const float* __restrict__ as,
        const float* __restrict__ ad, const int* __restrict__ off,
        const int* __restrict__ col, const float* __restrict__ bias,
        float* __restrict__ yout, unsigned* __restrict__ yb) {
    __shared__ float s_alpha[2][2][64][4];
    __shared__ int   s_src[2][2][64];
    __shared__ float2 s_red[2][32];

    const int wv   = (threadIdx.x >> 6) & 1;     // wave within node
    const int nd   = threadIdx.x >> 7;           // node within block
    const int lane = threadIdx.x & 63;
    const int n    = blockIdx.x * 2 + nd;        // 25000*2 == NN exactly
    const int e0   = off[n];
    const int tot  = off[n + 1] - e0;            // >=1 (self loop in CSR)
    const int hsel = lane >> 5;

    float4 adv = *(const float4*)&ad[n * HH + 4 * wv];   // this wave's 4 heads

    float d0 = 0.f, d1 = 0.f;                    // denom: heads 4wv+hsel, 4wv+2+hsel
    float acc[4] = {0.f, 0.f, 0.f, 0.f};

    for (int base = 0; base < tot; base += 64) {
        const int cnt = min(64, tot - base);
        // ---- phase A: numerators for this wave's 4 heads ----
        float n0, n1, n2, n3;
        if (lane < cnt) {
            int s = col[e0 + base + lane];
            s_src[nd][wv][lane] = s;
            float4 a = *(const float4*)&as[s * HH + 4 * wv];
            float e0v = a.x + adv.x, e1v = a.y + adv.y;
            float e2v = a.z + adv.z, e3v = a.w + adv.w;
            e0v = e0v > 0.f ? e0v : 0.2f * e0v;
            e1v = e1v > 0.f ? e1v : 0.2f * e1v;
            e2v = e2v > 0.f ? e2v : 0.2f * e2v;
            e3v = e3v > 0.f ? e3v : 0.2f * e3v;
            n0 = __expf(e0v); n1 = __expf(e1v);
            n2 = __expf(e2v); n3 = __expf(e3v);
            *(float4*)&s_alpha[nd][wv][lane][0] = make_float4(n0, n1, n2, n3);
        } else {
            n0 = n1 = n2 = n3 = 0.f;
        }
        // denom butterflies (4 heads)
        #define RED(v) { v += __shfl_xor(v, 1);  v += __shfl_xor(v, 2); \
                         v += __shfl_xor(v, 4);  v += __shfl_xor(v, 8); \
                         v += __shfl_xor(v, 16); v += __shfl_xor(v, 32); }
        RED(n0); RED(n1); RED(n2); RED(n3);
        #undef RED
        d0 += hsel ? n1 : n0;
        d1 += hsel ? n3 : n2;
        // ---- phase B: gather (2 u32 per lane per edge) ----
        #define STEP(jj) { \
            int sj = s_src[nd][wv][jj]; \
            const unsigned* _p = &hb[(size_t)sj * HU + wv * 128 + lane]; \
            unsigned u0 = _p[0], u1 = _p[64]; \
            float a0 = s_alpha[nd][wv][jj][hsel]; \
            float a1 = s_alpha[nd][wv][jj][2 + hsel]; \
            acc[0] += a0 * bf_lo(u0); acc[1] += a0 * bf_hi(u0); \
            acc[2] += a1 * bf_lo(u1); acc[3] += a1 * bf_hi(u1); }
        int j = 0;
        for (; j + 4 <= cnt; j += 4) { STEP(j); STEP(j + 1); STEP(j + 2); STEP(j + 3); }
        for (; j < cnt; ++j) STEP(j);
        #undef STEP
    }

    // normalize, sum this wave's 2 heads, fold lanes l and l^32
    float r0 = 1.f / d0, r1 = 1.f / d1;
    float sx = acc[0] * r0 + acc[2] * r1;
    float sy = acc[1] * r0 + acc[3] * r1;
    sx += __shfl_xor(sx, 32);
    sy += __shfl_xor(sy, 32);
    if (wv == 1 && lane < 32) s_red[nd][lane] = make_float2(sx, sy);
    __syncthreads();
    if (wv == 0 && lane < 32) {
        float2 o = s_red[nd][lane];
        float2 bv = *(const float2*)&bias[lane * 2];
        float vx = (sx + o.x) * 0.125f + bv.x;
        float vy = (sy + o.y) * 0.125f + bv.y;
        vx = vx > 0.f ? vx : (__expf(vx) - 1.f);
        vy = vy > 0.f ? vy : (__expf(vy) - 1.f);
        *(float2*)&yout[(size_t)n * CC + lane * 2] = make_float2(vx, vy);
        yb[(size_t)n * 32 + lane] = bf16pack(vx, vy);   // bf16 copy for next GEMM
    }
}

// ---------------- per-graph pooling (no atomics) ----------------

__global__ __launch_bounds__(256) void k_pool(
        const float* __restrict__ y, const int* __restrict__ batch,
        float* __restrict__ pooled, int layerOff) {
    __shared__ float red[256];
    const int g = blockIdx.x;
    const int t = threadIdx.x;
    int lo = 0, hi = NN;
    while (lo < hi) { int mid = (lo + hi) >> 1; if (batch[mid] < g) lo = mid + 1; else hi = mid; }
    const int nlo = lo;
    lo = nlo; hi = NN;
    while (lo < hi) { int mid = (lo + hi) >> 1; if (batch[mid] < g + 1) lo = mid + 1; else hi = mid; }
    const int nhi = lo;

    const int c = t & 63, r = t >> 6;
    float sum = 0.f;
    for (int n = nlo + r; n < nhi; n += 4) sum += y[(size_t)n * CC + c];
    red[t] = sum;
    __syncthreads();
    if (t < 64)
        pooled[g * (3 * CC) + layerOff + t] = red[t] + red[t + 64] + red[t + 128] + red[t + 192];
}

// ---------------- launch ----------------

extern "C" void kernel_launch(void* const* d_in, const int* in_sizes, int n_in,
                              void* d_out, int out_size, void* d_ws, size_t ws_size,
                              hipStream_t stream) {
    const float* x      = (const float*)d_in[0];
    const int*   ei     = (const int*)d_in[1];
    const int*   batch  = (const int*)d_in[2];
    const float* W0     = (const float*)d_in[4];
    const float* asrc0  = (const float*)d_in[5];
    const float* adst0  = (const float*)d_in[6];
    const float* b0     = (const float*)d_in[7];
    const float* W1     = (const float*)d_in[8];
    const float* asrc1  = (const float*)d_in[9];
    const float* adst1  = (const float*)d_in[10];
    const float* b1     = (const float*)d_in[11];
    const float* W2     = (const float*)d_in[12];
    const float* asrc2  = (const float*)d_in[13];
    const float* adst2  = (const float*)d_in[14];
    const float* b2     = (const float*)d_in[15];

    const int* src = ei;
    const int* dst = ei + EE;

    float* outp   = (float*)d_out;
    float* pooled = outp;                 // [64,192]
    float* hfinal = outp + POOL_SZ;       // [N,64]

    // workspace layout
    unsigned* hb     = (unsigned*)d_ws;                    // N*256 (bf16 x2)
    float*    y      = (float*)(hb + (size_t)NN * HU);     // N*64
    float*    as_buf = y + (size_t)NN * CC;                // N*8
    float*    ad_buf = as_buf + (size_t)NN * HH;           // N*8
    unsigned* xb     = (unsigned*)(ad_buf + (size_t)NN * HH); // N*64 (bf16 x2)
    unsigned* yb     = xb + (size_t)NN * 64;               // N*32 (bf16 x2)
    int*      off    = (int*)(yb + (size_t)NN * 32);       // N+1
    int*      cursor = off + (NN + 1);                     // N
    int*      cnt    = cursor + NN;                        // N
    int*      col    = cnt + NN;                           // ET
    int*      bsum   = col + ET;                           // <=256

    const int NB = (NN + SCAN_B - 1) / SCAN_B;   // 196

    k_prep<<<(NN * FIN / 8 + 255) / 256, 256, 0, stream>>>(x, xb, cnt);
    k_count<<<(EE + 255) / 256, 256, 0, stream>>>(dst, cnt);
    k_scan1<<<NB, SCAN_B, 0, stream>>>(cnt, off, bsum, NN);
    k_scan2<<<1, SCAN_B, 0, stream>>>(bsum, NB);
    k_scan3<<<(NN + 255) / 256, 256, 0, stream>>>(off, bsum, cursor, col, NN, ET);
    k_fill<<<(EE + 255) / 256, 256, 0, stream>>>(src, dst, cursor, col);

    dim3 ggrid((NN + 63) / 64, HH);

    const float* Ws_[3]  = {W0, W1, W2};
    const float* sa_[3]  = {asrc0, asrc1, asrc2};
    const float* da_[3]  = {adst0, adst1, adst2};
    const float* bb_[3]  = {b0, b1, b2};
    float* youts[3] = {y, y, hfinal};

    for (int L = 0; L < 3; ++L) {
        if (L == 0)
            k_gemm_mfma<FIN><<<ggrid, 256, 0, stream>>>(
                (const unsigned short*)xb, Ws_[0], sa_[0], da_[0],
                (unsigned short*)hb, as_buf, ad_buf, NN);
        else
            k_gemm_mfma<CC><<<ggrid, 256, 0, stream>>>(
                (const unsigned short*)yb, Ws_[L], sa_[L], da_[L],
                (unsigned short*)hb, as_buf, ad_buf, NN);
        k_aggw<<<NN / 2, 256, 0, stream>>>(hb, as_buf, ad_buf, off, col,
                                           bb_[L], youts[L], yb);
        k_pool<<<GG, 256, 0, stream>>>(youts[L], batch, pooled, L * CC);
    }
}